// Round 1
// baseline (6155.180 us; speedup 1.0000x reference)
//
#include <hip/hip_runtime.h>
#include <math.h>

#define S_LEN 256
#define NCELL 8
#define HID 16
#define MEM 20
#define WROW 129          // NT+1
#define WPAD 132          // padded ring row (16B-aligned rows)
#define NB 4              // batch elements per block
#define NTHR 256

__device__ __forceinline__ float sigm(float v) { return 1.0f / (1.0f + __expf(-v)); }
__device__ __forceinline__ float tanh_f(float v) { return 1.0f - 2.0f / (__expf(2.0f * v) + 1.0f); }
__device__ __forceinline__ float dot4(float4 a, float4 b) {
    return fmaf(a.x, b.x, fmaf(a.y, b.y, fmaf(a.z, b.z, a.w * b.w)));
}

// W1 [64][2580] -> W1T [2580][64] so phase-B global reads are coalesced.
__global__ __launch_bounds__(256)
void transpose_w1(const float* __restrict__ W1, float* __restrict__ W1T) {
    int idx = blockIdx.x * 256 + threadIdx.x;
    if (idx < 2580 * 64) {
        int r = idx >> 6, j = idx & 63;
        W1T[idx] = W1[j * 2580 + r];
    }
}

__global__ __launch_bounds__(NTHR)
void mmoe_kernel(const float* __restrict__ x, const float* __restrict__ pred0,
                 const float* __restrict__ gate0,
                 const float* __restrict__ W_ih, const float* __restrict__ W_hh,
                 const float* __restrict__ b_ih, const float* __restrict__ b_hh,
                 const float* __restrict__ W_o, const float* __restrict__ b_o,
                 const float* __restrict__ W1T, const float* __restrict__ b1,
                 const float* __restrict__ W2, const float* __restrict__ b2,
                 const float* __restrict__ Wg, const float* __restrict__ bg,
                 const float* __restrict__ Wa_ih, const float* __restrict__ Wa_hh,
                 const float* __restrict__ ba_ih, const float* __restrict__ ba_hh,
                 float* __restrict__ out)
{
    __shared__ float ring[NB * MEM * WPAD];           // 42240 B  (w-row ring buffer = mem)
    __shared__ float ehS[NB][HID], ecS[NB][HID];      // combined expert state
    __shared__ float nhS[NB][NCELL][HID], ncS[NB][NCELL][HID];
    __shared__ float oS[NB][NCELL];
    __shared__ float predS[NB];
    __shared__ float gateS[NB][NCELL];
    __shared__ float ahS[2][NB][HID], acS[2][NB][HID];
    __shared__ float e1S[NB][64];
    __shared__ float aiS[NB][HID];
    __shared__ float red[4][NB][64];                  // phase-B split-K partials
    __shared__ float zbuf[NB][64];
    __shared__ float glog[NB][NCELL];

    const int tid = threadIdx.x;
    const int b0 = blockIdx.x * NB;

    // ---- init recurrent state ----
    for (int i = tid; i < NB * MEM * WPAD; i += NTHR)
        ring[i] = ((i % WPAD) == 128) ? 0.5f : 0.0f;   // mem0: zeros, last col 0.5
    if (tid < NB * HID) {
        int b = tid >> 4, h = tid & 15;
        ehS[b][h] = 0.f; ecS[b][h] = 0.f;
        ahS[0][b][h] = 0.f; ahS[1][b][h] = 0.f;
        acS[0][b][h] = 0.f; acS[1][b][h] = 0.f;
    }
    if (tid < NB) predS[tid] = pred0[b0 + tid];
    if (tid < NB * NCELL) {
        int b = tid >> 3, c = tid & 7;
        gateS[b][c] = gate0[(b0 + b) * NCELL + c];
    }
    __syncthreads();

    int head = 0;
    for (int t = 0; t < S_LEN; ++t) {
        head = (head == 0) ? (MEM - 1) : (head - 1);   // new row slot (row 0 of mem)

        // ---- Phase A: 8 expert LSTM cells, shared state; write w-row into ring ----
        #pragma unroll
        for (int it = 0; it < 2; ++it) {
            int item = tid + it * NTHR;                // 512 items: (b, c, h)
            int b = item >> 7, rem = item & 127, c = rem >> 4, h = rem & 15;
            float xv = x[(b0 + b) * S_LEN + t];
            const float4* ep = (const float4*)&ehS[b][0];
            float4 e0 = ep[0], e1v = ep[1], e2 = ep[2], e3 = ep[3];
            float zg[4];
            #pragma unroll
            for (int gi = 0; gi < 4; ++gi) {           // gates i,f,g,o
                int g = c * 64 + gi * 16 + h;
                const float4* wr = (const float4*)&W_hh[g * 16];
                float z = b_ih[g] + b_hh[g] + xv * W_ih[g];
                z += dot4(e0, wr[0]) + dot4(e1v, wr[1]) + dot4(e2, wr[2]) + dot4(e3, wr[3]);
                zg[gi] = z;
            }
            float cc = ecS[b][h];
            float c2 = sigm(zg[1]) * cc + sigm(zg[0]) * tanh_f(zg[2]);
            float hv = sigm(zg[3]) * tanh_f(c2);
            nhS[b][c][h] = hv; ncS[b][c][h] = c2;
            ring[(b * MEM + head) * WPAD + c * HID + h] = hv;
        }
        if (tid < NB) {                                // error -> last col of new row
            float e = x[(b0 + tid) * S_LEN + t] - predS[tid];
            ring[(tid * MEM + head) * WPAD + 128] = e;
        }
        __syncthreads();

        // ---- Phase B: e1_pre = mem_flat @ W1.T  (threads: 16 jq x 4 b x 4 msplit) ----
        {
            const int jq = tid & 15, bb = (tid >> 4) & 3, ms = tid >> 6;
            const float* ringB = &ring[bb * MEM * WPAD];
            float4 acc = make_float4(0.f, 0.f, 0.f, 0.f);
            for (int mi = 0; mi < 5; ++mi) {
                int m = ms * 5 + mi;
                int slot = head + m; if (slot >= MEM) slot -= MEM;
                const float* rowp = &ringB[slot * WPAD];
                const float4* w1p = (const float4*)&W1T[m * WROW * 64];
                #pragma unroll 4
                for (int k4 = 0; k4 < 32; ++k4) {
                    float4 rv = *(const float4*)&rowp[k4 * 4];
                    float4 wa = w1p[(k4 * 4 + 0) * 16 + jq];
                    float4 wb = w1p[(k4 * 4 + 1) * 16 + jq];
                    float4 wc = w1p[(k4 * 4 + 2) * 16 + jq];
                    float4 wd = w1p[(k4 * 4 + 3) * 16 + jq];
                    acc.x = fmaf(wa.x, rv.x, acc.x);
                    acc.y = fmaf(wa.y, rv.x, acc.y);
                    acc.z = fmaf(wa.z, rv.x, acc.z);
                    acc.w = fmaf(wa.w, rv.x, acc.w);
                    acc.x = fmaf(wb.x, rv.y, acc.x);
                    acc.y = fmaf(wb.y, rv.y, acc.y);
                    acc.z = fmaf(wb.z, rv.y, acc.z);
                    acc.w = fmaf(wb.w, rv.y, acc.w);
                    acc.x = fmaf(wc.x, rv.z, acc.x);
                    acc.y = fmaf(wc.y, rv.z, acc.y);
                    acc.z = fmaf(wc.z, rv.z, acc.z);
                    acc.w = fmaf(wc.w, rv.z, acc.w);
                    acc.x = fmaf(wd.x, rv.w, acc.x);
                    acc.y = fmaf(wd.y, rv.w, acc.y);
                    acc.z = fmaf(wd.z, rv.w, acc.z);
                    acc.w = fmaf(wd.w, rv.w, acc.w);
                }
                float rl = rowp[128];                  // k = 128 remainder
                float4 we = w1p[128 * 16 + jq];
                acc.x = fmaf(we.x, rl, acc.x);
                acc.y = fmaf(we.y, rl, acc.y);
                acc.z = fmaf(we.z, rl, acc.z);
                acc.w = fmaf(we.w, rl, acc.w);
            }
            *(float4*)&red[ms][bb][jq * 4] = acc;
        }
        __syncthreads();
        {   // reduce split-K + bias + relu
            int bb = tid >> 6, j = tid & 63;
            float v = b1[j] + red[0][bb][j] + red[1][bb][j] + red[2][bb][j] + red[3][bb][j];
            e1S[bb][j] = fmaxf(v, 0.f);
        }
        __syncthreads();

        // ---- Phase C: layer2 MLP (4b x 16i) + expert heads o (4b x 8c) ----
        if (tid < 64) {
            int bb = tid >> 4, i = tid & 15;
            const float4* w2p = (const float4*)&W2[i * 64];
            const float4* epq = (const float4*)&e1S[bb][0];
            float s = b2[i];
            #pragma unroll
            for (int q = 0; q < 16; ++q) s += dot4(w2p[q], epq[q]);
            aiS[bb][i] = fmaxf(s, 0.f);
        } else if (tid < 96) {
            int q = tid - 64; int bb = q >> 3, c = q & 7;
            float s = b_o[c];
            #pragma unroll
            for (int h = 0; h < 16; ++h) s = fmaf(nhS[bb][c][h], W_o[c * 16 + h], s);
            oS[bb][c] = s;
        }
        __syncthreads();

        // ---- Phase D: 2-layer agent LSTM ----
        for (int l = 0; l < 2; ++l) {
            {
                int bb = tid >> 6, g = tid & 63;
                const float4* ip = (l == 0) ? (const float4*)&aiS[bb][0]
                                            : (const float4*)&ahS[0][bb][0];
                const float4* hp = (const float4*)&ahS[l][bb][0];
                const float4* wi = (const float4*)&Wa_ih[(l * 64 + g) * 16];
                const float4* wh = (const float4*)&Wa_hh[(l * 64 + g) * 16];
                float z = ba_ih[l * 64 + g] + ba_hh[l * 64 + g];
                #pragma unroll
                for (int q = 0; q < 4; ++q) z += dot4(ip[q], wi[q]) + dot4(hp[q], wh[q]);
                zbuf[bb][g] = z;
            }
            __syncthreads();
            if (tid < 64) {
                int bb = tid >> 4, h = tid & 15;
                float zi = zbuf[bb][h], zf = zbuf[bb][16 + h];
                float zg_ = zbuf[bb][32 + h], zo = zbuf[bb][48 + h];
                float c2 = sigm(zf) * acS[l][bb][h] + sigm(zi) * tanh_f(zg_);
                acS[l][bb][h] = c2;
                ahS[l][bb][h] = sigm(zo) * tanh_f(c2);
            }
            __syncthreads();
        }

        // ---- gate logits ----
        if (tid < 32) {
            int bb = tid >> 3, c = tid & 7;
            const float4* wg = (const float4*)&Wg[c * 16];
            const float4* hp = (const float4*)&ahS[1][bb][0];
            float s = bg[c];
            #pragma unroll
            for (int q = 0; q < 4; ++q) s += dot4(wg[q], hp[q]);
            glog[bb][c] = s;
        }
        __syncthreads();
        // ---- softmax + theta blend (1 thread per batch) ----
        if (tid < NB) {
            int bb = tid;
            float mx = glog[bb][0];
            #pragma unroll
            for (int c = 1; c < 8; ++c) mx = fmaxf(mx, glog[bb][c]);
            float ex[8], sum = 0.f;
            #pragma unroll
            for (int c = 0; c < 8; ++c) { ex[c] = __expf(glog[bb][c] - mx); sum += ex[c]; }
            float inv = 1.f / sum;
            float th = 0.f;
            #pragma unroll
            for (int m = 0; m < 10; ++m) {
                int slot = head + m; if (slot >= MEM) slot -= MEM;
                th += fabsf(ring[(bb * MEM + slot) * WPAD + 128]);
            }
            th *= 0.25f;                                // mean*2.5 = sum/10*2.5
            th = fminf(fmaxf(th, 0.f), 1.f);
            #pragma unroll
            for (int c = 0; c < 8; ++c)
                gateS[bb][c] = ex[c] * inv * th + gateS[bb][c] * (1.f - th);
        }
        __syncthreads();
        // ---- combine: eh/ec/pred via gate ----
        if (tid < 64) {
            int bb = tid >> 4, h = tid & 15;
            float se = 0.f, sc = 0.f;
            #pragma unroll
            for (int c = 0; c < 8; ++c) {
                float g = gateS[bb][c];
                se = fmaf(g, nhS[bb][c][h], se);
                sc = fmaf(g, ncS[bb][c][h], sc);
            }
            ehS[bb][h] = se; ecS[bb][h] = sc;
        } else if (tid < 64 + NB) {
            int bb = tid - 64;
            float s = 0.f;
            #pragma unroll
            for (int c = 0; c < 8; ++c) s = fmaf(gateS[bb][c], oS[bb][c], s);
            predS[bb] = s;
            out[(b0 + bb) * S_LEN + t] = s;
        }
        __syncthreads();
    }
}

extern "C" void kernel_launch(void* const* d_in, const int* in_sizes, int n_in,
                              void* d_out, int out_size, void* d_ws, size_t ws_size,
                              hipStream_t stream) {
    const float* xp    = (const float*)d_in[0];
    const float* pred0 = (const float*)d_in[1];
    const float* gate0 = (const float*)d_in[2];
    const float* W_ih  = (const float*)d_in[3];
    const float* W_hh  = (const float*)d_in[4];
    const float* b_ih  = (const float*)d_in[5];
    const float* b_hh  = (const float*)d_in[6];
    const float* W_o   = (const float*)d_in[7];
    const float* b_o   = (const float*)d_in[8];
    const float* W1    = (const float*)d_in[9];
    const float* b1    = (const float*)d_in[10];
    const float* W2    = (const float*)d_in[11];
    const float* b2    = (const float*)d_in[12];
    const float* Wg    = (const float*)d_in[13];
    const float* bg    = (const float*)d_in[14];
    const float* Wa_ih = (const float*)d_in[15];
    const float* Wa_hh = (const float*)d_in[16];
    const float* ba_ih = (const float*)d_in[17];
    const float* ba_hh = (const float*)d_in[18];
    float* W1T = (float*)d_ws;                         // 2580*64*4 = 660480 B

    transpose_w1<<<(2580 * 64 + 255) / 256, 256, 0, stream>>>(W1, W1T);
    mmoe_kernel<<<512 / NB, NTHR, 0, stream>>>(
        xp, pred0, gate0, W_ih, W_hh, b_ih, b_hh, W_o, b_o,
        W1T, b1, W2, b2, Wg, bg, Wa_ih, Wa_hh, ba_ih, ba_hh,
        (float*)d_out);
}

// Round 2
// 1938.355 us; speedup vs baseline: 3.1755x; 3.1755x over previous
//
#include <hip/hip_runtime.h>
#include <math.h>

#define S_LEN 256
#define NCELL 8
#define HID 16
#define MEM 20
#define NB 2
#define NTHR 256

typedef _Float16 h2 __attribute__((ext_vector_type(2)));

#if defined(__has_builtin)
#if __has_builtin(__builtin_amdgcn_fdot2)
#define HAVE_FDOT2 1
#endif
#endif

__device__ __forceinline__ float sigm(float v) { return 1.0f / (1.0f + __expf(-v)); }
__device__ __forceinline__ float tanh_f(float v) { return 1.0f - 2.0f / (__expf(2.0f * v) + 1.0f); }
__device__ __forceinline__ float dot4(float4 a, float4 b) {
    return fmaf(a.x, b.x, fmaf(a.y, b.y, fmaf(a.z, b.z, a.w * b.w)));
}
__device__ __forceinline__ h2 bc_h2(float f) { return __builtin_bit_cast(h2, f); }
__device__ __forceinline__ float dot2acc(h2 a, h2 w, float c) {
#ifdef HAVE_FDOT2
    return __builtin_amdgcn_fdot2(a, w, c, false);
#else
    return fmaf((float)a.x, (float)w.x, fmaf((float)a.y, (float)w.y, c));
#endif
}

__global__ __launch_bounds__(NTHR, 1)
void mmoe_kernel(const float* __restrict__ x, const float* __restrict__ pred0,
                 const float* __restrict__ gate0,
                 const float* __restrict__ W_ih, const float* __restrict__ W_hh,
                 const float* __restrict__ b_ih, const float* __restrict__ b_hh,
                 const float* __restrict__ W_o, const float* __restrict__ b_o,
                 const float* __restrict__ W1, const float* __restrict__ b1,
                 const float* __restrict__ W2, const float* __restrict__ b2,
                 const float* __restrict__ Wg, const float* __restrict__ bg,
                 const float* __restrict__ Wa_ih, const float* __restrict__ Wa_hh,
                 const float* __restrict__ ba_ih, const float* __restrict__ ba_hh,
                 float* __restrict__ out)
{
    // ---- LDS (~100 KB, 1 block/CU) ----
    __shared__ __align__(16) _Float16 ringH[NB][MEM][128];   // h-part of memory rows, f16
    __shared__ float errS[NB][MEM];                          // error column, f32 (precision)
    __shared__ float Whh_l[512 * 20];                        // stride 20 (bank pad)
    __shared__ float Wih_l[512], bias_l[512];
    __shared__ float WaI[2][64 * 20], WaH[2][64 * 20];       // agent weights, stride 20
    __shared__ float ba_l[2][64];
    __shared__ float W2_l[16 * 68];                          // stride 68 (bank pad)
    __shared__ float b2_l[16];
    __shared__ float Wg_l[8][16], bg_l[8], Wo_l[8][16], bo_l[8];
    __shared__ float Werr_l[MEM * 64];                       // W1 col-128 slices
    __shared__ float b1_l[64];
    __shared__ float xS[NB][S_LEN];
    __shared__ float ehS[NB][HID], ecS[NB][HID];
    __shared__ float nhS[NB][NCELL][HID], ncS[NB][NCELL][HID];
    __shared__ float oS[NB][NCELL], predS[NB], gateS[NB][NCELL];
    __shared__ float ahS[2][NB][HID], acS[2][NB][HID];
    __shared__ float e1S[NB][64], aiS[NB][HID], zbuf[NB][64], glog[NB][NCELL];
    __shared__ __align__(16) float red[16][NB][64];          // phase-B split-K partials

    const int tid = threadIdx.x;
    const int b0 = blockIdx.x * NB;
    const int jg = tid & 15, kg = tid >> 4;                  // phase-B thread identity
    const int j0 = jg * 4, c0 = kg * 8;

    // ---- one-time staging: global -> LDS ----
    for (int i = tid; i < 512 * 16; i += NTHR) { int g = i >> 4, q = i & 15; Whh_l[g * 20 + q] = W_hh[i]; }
    for (int i = tid; i < 512; i += NTHR) { Wih_l[i] = W_ih[i]; bias_l[i] = b_ih[i] + b_hh[i]; }
    for (int i = tid; i < 2048; i += NTHR) {
        int l = i >> 10, r = i & 1023, g = r >> 4, q = r & 15;
        WaI[l][g * 20 + q] = Wa_ih[i]; WaH[l][g * 20 + q] = Wa_hh[i];
    }
    for (int i = tid; i < 128; i += NTHR) { int l = i >> 6, g = i & 63; ba_l[l][g] = ba_ih[i] + ba_hh[i]; }
    for (int i = tid; i < 1024; i += NTHR) { int r = i >> 6, q = i & 63; W2_l[r * 68 + q] = W2[i]; }
    for (int i = tid; i < 1280; i += NTHR) { int m = i >> 6, j = i & 63; Werr_l[i] = W1[j * 2580 + m * 129 + 128]; }
    if (tid < 64) b1_l[tid] = b1[tid];
    if (tid < 16) b2_l[tid] = b2[tid];
    if (tid < 128) { int c = tid >> 4, h = tid & 15; Wg_l[c][h] = Wg[tid]; Wo_l[c][h] = W_o[tid]; }
    if (tid < 8) { bg_l[tid] = bg[tid]; bo_l[tid] = b_o[tid]; }
    for (int i = tid; i < NB * S_LEN; i += NTHR) { int b = i >> 8, s = i & 255; xS[b][s] = x[(b0 + b) * S_LEN + s]; }
    // state init
    for (int i = tid; i < NB * MEM * 128; i += NTHR) ((_Float16*)ringH)[i] = (_Float16)0.0f;
    if (tid < NB * MEM) { int b = tid / MEM, m = tid % MEM; errS[b][m] = 0.5f; }
    if (tid < NB * HID) {
        int b = tid >> 4, h = tid & 15;
        ehS[b][h] = 0.f; ecS[b][h] = 0.f;
        ahS[0][b][h] = 0.f; ahS[1][b][h] = 0.f;
        acS[0][b][h] = 0.f; acS[1][b][h] = 0.f;
    }
    if (tid < NB) predS[tid] = pred0[b0 + tid];
    if (tid < NB * NCELL) { int b = tid >> 3, c = tid & 7; gateS[b][c] = gate0[(b0 + b) * NCELL + c]; }

    // ---- register-resident W1 slice (f16): [m][col-pair p][jj] ----
    h2 w1r[MEM][4][4];
    #pragma unroll
    for (int m = 0; m < MEM; ++m)
        #pragma unroll
        for (int p = 0; p < 4; ++p)
            #pragma unroll
            for (int jj = 0; jj < 4; ++jj) {
                const float* wp = &W1[(j0 + jj) * 2580 + m * 129 + c0 + 2 * p];
                h2 w; w.x = (_Float16)wp[0]; w.y = (_Float16)wp[1];
                w1r[m][p][jj] = w;
            }
    __syncthreads();

    int head = 0;
    #pragma unroll 1
    for (int t = 0; t < S_LEN; ++t) {
        head = (head == 0) ? (MEM - 1) : (head - 1);

        // ---- Phase A: 8 expert LSTM cells (256 items = NB*8*16) ----
        {
            int b = tid >> 7, c = (tid >> 4) & 7, h = tid & 15;
            float xv = xS[b][t];
            const float4* ep = (const float4*)&ehS[b][0];
            float4 e0 = ep[0], e1v = ep[1], e2 = ep[2], e3 = ep[3];
            float zg[4];
            #pragma unroll
            for (int gi = 0; gi < 4; ++gi) {
                int g = c * 64 + gi * 16 + h;
                const float* wr = &Whh_l[g * 20];
                float z = bias_l[g] + xv * Wih_l[g];
                z += dot4(e0, *(const float4*)&wr[0]) + dot4(e1v, *(const float4*)&wr[4])
                   + dot4(e2, *(const float4*)&wr[8]) + dot4(e3, *(const float4*)&wr[12]);
                zg[gi] = z;
            }
            float cc = ecS[b][h];
            float c2 = sigm(zg[1]) * cc + sigm(zg[0]) * tanh_f(zg[2]);
            float hv = sigm(zg[3]) * tanh_f(c2);
            nhS[b][c][h] = hv; ncS[b][c][h] = c2;
            ringH[b][head][c * 16 + h] = (_Float16)hv;
        }
        if (tid < NB) errS[tid][head] = xS[tid][t] - predS[tid];
        __syncthreads();

        // ---- Phase B: e1_pre partials via register-resident f16 W1 + v_dot2 ----
        {
            float acc0[4] = {0.f, 0.f, 0.f, 0.f};
            float acc1[4] = {0.f, 0.f, 0.f, 0.f};
            float4 avA = *(const float4*)&ringH[0][head][c0];
            float4 avB = *(const float4*)&ringH[1][head][c0];
            #pragma unroll
            for (int m = 0; m < MEM; ++m) {
                float4 cA = avA, cB = avB;
                if (m < MEM - 1) {
                    int s2 = head + m + 1; if (s2 >= MEM) s2 -= MEM;
                    avA = *(const float4*)&ringH[0][s2][c0];
                    avB = *(const float4*)&ringH[1][s2][c0];
                }
                h2 aA[4] = {bc_h2(cA.x), bc_h2(cA.y), bc_h2(cA.z), bc_h2(cA.w)};
                h2 aB[4] = {bc_h2(cB.x), bc_h2(cB.y), bc_h2(cB.z), bc_h2(cB.w)};
                #pragma unroll
                for (int p = 0; p < 4; ++p)
                    #pragma unroll
                    for (int jj = 0; jj < 4; ++jj) {
                        acc0[jj] = dot2acc(aA[p], w1r[m][p][jj], acc0[jj]);
                        acc1[jj] = dot2acc(aB[p], w1r[m][p][jj], acc1[jj]);
                    }
            }
            *(float4*)&red[kg][0][j0] = make_float4(acc0[0], acc0[1], acc0[2], acc0[3]);
            *(float4*)&red[kg][1][j0] = make_float4(acc1[0], acc1[1], acc1[2], acc1[3]);
        }
        __syncthreads();
        if (tid < 128) {  // reduce 16 partials + fp32 error column + bias + relu
            int bb = tid >> 6, j = tid & 63;
            float v = b1_l[j];
            #pragma unroll
            for (int g = 0; g < 16; ++g) v += red[g][bb][j];
            #pragma unroll
            for (int m = 0; m < MEM; ++m) {
                int s = head + m; if (s >= MEM) s -= MEM;
                v = fmaf(Werr_l[m * 64 + j], errS[bb][s], v);
            }
            e1S[bb][j] = fmaxf(v, 0.f);
        }
        __syncthreads();

        // ---- Phase C: layer-2 MLP + expert heads ----
        if (tid < 32) {
            int bb = tid >> 4, i = tid & 15;
            const float4* epq = (const float4*)&e1S[bb][0];
            float s = b2_l[i];
            #pragma unroll
            for (int q = 0; q < 16; ++q) s += dot4(*(const float4*)&W2_l[i * 68 + q * 4], epq[q]);
            aiS[bb][i] = fmaxf(s, 0.f);
        } else if (tid < 48) {
            int q = tid - 32, bb = q >> 3, c = q & 7;
            float s = bo_l[c];
            #pragma unroll
            for (int h = 0; h < 16; ++h) s = fmaf(nhS[bb][c][h], Wo_l[c][h], s);
            oS[bb][c] = s;
        }
        __syncthreads();

        // ---- Phase D: 2-layer agent LSTM ----
        #pragma unroll
        for (int l = 0; l < 2; ++l) {
            if (tid < 128) {
                int bb = tid >> 6, g = tid & 63;
                const float4* ip = (l == 0) ? (const float4*)&aiS[bb][0]
                                            : (const float4*)&ahS[0][bb][0];
                const float4* hp = (const float4*)&ahS[l][bb][0];
                float z = ba_l[l][g];
                #pragma unroll
                for (int q = 0; q < 4; ++q)
                    z += dot4(ip[q], *(const float4*)&WaI[l][g * 20 + q * 4])
                       + dot4(hp[q], *(const float4*)&WaH[l][g * 20 + q * 4]);
                zbuf[bb][g] = z;
            }
            __syncthreads();
            if (tid < 32) {
                int bb = tid >> 4, h = tid & 15;
                float zi = zbuf[bb][h], zf = zbuf[bb][16 + h];
                float zg_ = zbuf[bb][32 + h], zo = zbuf[bb][48 + h];
                float c2 = sigm(zf) * acS[l][bb][h] + sigm(zi) * tanh_f(zg_);
                acS[l][bb][h] = c2;
                ahS[l][bb][h] = sigm(zo) * tanh_f(c2);
            }
            __syncthreads();
        }

        // ---- gate logits ----
        if (tid < 16) {
            int bb = tid >> 3, c = tid & 7;
            const float4* hp = (const float4*)&ahS[1][bb][0];
            const float4* wg = (const float4*)&Wg_l[c][0];
            float s = bg_l[c];
            #pragma unroll
            for (int q = 0; q < 4; ++q) s += dot4(wg[q], hp[q]);
            glog[bb][c] = s;
        }
        __syncthreads();
        // ---- softmax + theta blend ----
        if (tid < NB) {
            int bb = tid;
            float mx = glog[bb][0];
            #pragma unroll
            for (int c = 1; c < 8; ++c) mx = fmaxf(mx, glog[bb][c]);
            float ex[8], sum = 0.f;
            #pragma unroll
            for (int c = 0; c < 8; ++c) { ex[c] = __expf(glog[bb][c] - mx); sum += ex[c]; }
            float inv = 1.f / sum;
            float th = 0.f;
            #pragma unroll
            for (int m = 0; m < 10; ++m) {
                int s = head + m; if (s >= MEM) s -= MEM;
                th += fabsf(errS[bb][s]);
            }
            th *= 0.25f;
            th = fminf(fmaxf(th, 0.f), 1.f);
            #pragma unroll
            for (int c = 0; c < 8; ++c)
                gateS[bb][c] = ex[c] * inv * th + gateS[bb][c] * (1.f - th);
        }
        __syncthreads();
        // ---- combine ----
        if (tid < 32) {
            int bb = tid >> 4, h = tid & 15;
            float se = 0.f, sc = 0.f;
            #pragma unroll
            for (int c = 0; c < 8; ++c) {
                float g = gateS[bb][c];
                se = fmaf(g, nhS[bb][c][h], se);
                sc = fmaf(g, ncS[bb][c][h], sc);
            }
            ehS[bb][h] = se; ecS[bb][h] = sc;
        } else if (tid < 32 + NB) {
            int bb = tid - 32;
            float s = 0.f;
            #pragma unroll
            for (int c = 0; c < 8; ++c) s = fmaf(gateS[bb][c], oS[bb][c], s);
            predS[bb] = s;
            out[(b0 + bb) * S_LEN + t] = s;
        }
        __syncthreads();
    }
}

extern "C" void kernel_launch(void* const* d_in, const int* in_sizes, int n_in,
                              void* d_out, int out_size, void* d_ws, size_t ws_size,
                              hipStream_t stream) {
    const float* xp    = (const float*)d_in[0];
    const float* pred0 = (const float*)d_in[1];
    const float* gate0 = (const float*)d_in[2];
    const float* W_ih  = (const float*)d_in[3];
    const float* W_hh  = (const float*)d_in[4];
    const float* b_ih  = (const float*)d_in[5];
    const float* b_hh  = (const float*)d_in[6];
    const float* W_o   = (const float*)d_in[7];
    const float* b_o   = (const float*)d_in[8];
    const float* W1    = (const float*)d_in[9];
    const float* b1    = (const float*)d_in[10];
    const float* W2    = (const float*)d_in[11];
    const float* b2    = (const float*)d_in[12];
    const float* Wg    = (const float*)d_in[13];
    const float* bg    = (const float*)d_in[14];
    const float* Wa_ih = (const float*)d_in[15];
    const float* Wa_hh = (const float*)d_in[16];
    const float* ba_ih = (const float*)d_in[17];
    const float* ba_hh = (const float*)d_in[18];

    mmoe_kernel<<<512 / NB, NTHR, 0, stream>>>(
        xp, pred0, gate0, W_ih, W_hh, b_ih, b_hh, W_o, b_o,
        W1, b1, W2, b2, Wg, bg, Wa_ih, Wa_hh, ba_ih, ba_hh,
        (float*)d_out);
}

// Round 3
// 1823.041 us; speedup vs baseline: 3.3763x; 1.0633x over previous
//
#include <hip/hip_runtime.h>
#include <math.h>

#define S_LEN 256
#define NCELL 8
#define HID 16
#define MEM 20
#define NB 2
#define NTHR 512
#define KT 32
#define RPAD 68

typedef _Float16 h2 __attribute__((ext_vector_type(2)));
typedef _Float16 h4 __attribute__((ext_vector_type(4)));

#if defined(__has_builtin)
#if __has_builtin(__builtin_amdgcn_fdot2)
#define HAVE_FDOT2 1
#endif
#endif

__device__ __forceinline__ float sigm(float v) { return 1.0f / (1.0f + __expf(-v)); }
__device__ __forceinline__ float tanh_f(float v) { return 1.0f - 2.0f / (__expf(2.0f * v) + 1.0f); }
__device__ __forceinline__ float dot4(float4 a, float4 b) {
    return fmaf(a.x, b.x, fmaf(a.y, b.y, fmaf(a.z, b.z, a.w * b.w)));
}
__device__ __forceinline__ float dot2acc(h2 a, h2 w, float c) {
#ifdef HAVE_FDOT2
    return __builtin_amdgcn_fdot2(a, w, c, false);
#else
    return fmaf((float)a.x, (float)w.x, fmaf((float)a.y, (float)w.y, c));
#endif
}

__global__ __launch_bounds__(NTHR, 1)
void mmoe_kernel(const float* __restrict__ x, const float* __restrict__ pred0,
                 const float* __restrict__ gate0,
                 const float* __restrict__ W_ih, const float* __restrict__ W_hh,
                 const float* __restrict__ b_ih, const float* __restrict__ b_hh,
                 const float* __restrict__ W_o, const float* __restrict__ b_o,
                 const float* __restrict__ W1, const float* __restrict__ b1,
                 const float* __restrict__ W2, const float* __restrict__ b2,
                 const float* __restrict__ Wg, const float* __restrict__ bg,
                 const float* __restrict__ Wa_ih, const float* __restrict__ Wa_hh,
                 const float* __restrict__ ba_ih, const float* __restrict__ ba_hh,
                 float* __restrict__ out)
{
    __shared__ __align__(16) _Float16 ringH[NB][MEM][128];   // memory rows (h part), f16
    __shared__ float errS[NB][MEM];                          // error column, f32
    __shared__ __align__(16) float Whh_l[512 * 20];          // stride 20 (bank pad)
    __shared__ float Wih_l[512], bias_l[512];
    __shared__ __align__(16) float WaI[2][64 * 20], WaH[2][64 * 20];
    __shared__ float ba_l[2][64];
    __shared__ __align__(16) float W2_l[16 * 68];
    __shared__ float b2_l[16];
    __shared__ __align__(16) float Wg_l[8][16], Wo_l[8][16];
    __shared__ float bg_l[8], bo_l[8];
    __shared__ float Werr_l[MEM * 64];                       // W1 col-128 slices (f32)
    __shared__ float b1_l[64];
    __shared__ float xS[NB][S_LEN];
    __shared__ __align__(16) float ehS[NB][HID], ecS[NB][HID];
    __shared__ __align__(16) float nhS[NB][NCELL][HID], ncS[NB][NCELL][HID];
    __shared__ float oS[NB][NCELL], predS[NB], gateS[NB][NCELL];
    __shared__ __align__(16) float ahS[2][NB][HID], acS[2][NB][HID];
    __shared__ __align__(16) float e1S[NB][64], aiS[NB][HID];
    __shared__ __align__(16) float glog[NB][8];
    __shared__ __align__(16) float red[NB][KT][RPAD];        // phase-B split-K partials

    const int tid = threadIdx.x;
    const int b0 = blockIdx.x * NB;
    const int jg = tid & 15, kg = tid >> 4;                  // phase-B identity: 16 j-groups x 32 k-groups
    const int j0 = jg * 4, c0 = kg * 4;                      // 4 j-cols, 4 f16 k-cols per m-row

    // ---- one-time staging: global -> LDS ----
    for (int i = tid; i < 512 * 16; i += NTHR) { int g = i >> 4, q = i & 15; Whh_l[g * 20 + q] = W_hh[i]; }
    for (int i = tid; i < 512; i += NTHR) { Wih_l[i] = W_ih[i]; bias_l[i] = b_ih[i] + b_hh[i]; }
    for (int i = tid; i < 2048; i += NTHR) {
        int l = i >> 10, r = i & 1023, g = r >> 4, q = r & 15;
        WaI[l][g * 20 + q] = Wa_ih[i]; WaH[l][g * 20 + q] = Wa_hh[i];
    }
    for (int i = tid; i < 128; i += NTHR) { int l = i >> 6, g = i & 63; ba_l[l][g] = ba_ih[i] + ba_hh[i]; }
    for (int i = tid; i < 1024; i += NTHR) { int r = i >> 6, q = i & 63; W2_l[r * 68 + q] = W2[i]; }
    for (int i = tid; i < 1280; i += NTHR) { int m = i >> 6, j = i & 63; Werr_l[i] = W1[j * 2580 + m * 129 + 128]; }
    if (tid < 64) b1_l[tid] = b1[tid];
    if (tid < 16) b2_l[tid] = b2[tid];
    if (tid < 128) { int c = tid >> 4, h = tid & 15; Wg_l[c][h] = Wg[tid]; Wo_l[c][h] = W_o[tid]; }
    if (tid < 8) { bg_l[tid] = bg[tid]; bo_l[tid] = b_o[tid]; }
    for (int i = tid; i < NB * S_LEN; i += NTHR) { int b = i >> 8, s = i & 255; xS[b][s] = x[(b0 + b) * S_LEN + s]; }
    // state init
    for (int i = tid; i < NB * MEM * 128; i += NTHR) ((_Float16*)ringH)[i] = (_Float16)0.0f;
    if (tid < NB * MEM) { int b = tid / MEM, m = tid % MEM; errS[b][m] = 0.5f; }
    if (tid < NB * HID) {
        int b = tid >> 4, h = tid & 15;
        ehS[b][h] = 0.f; ecS[b][h] = 0.f;
        ahS[0][b][h] = 0.f; ahS[1][b][h] = 0.f;
        acS[0][b][h] = 0.f; acS[1][b][h] = 0.f;
    }
    if (tid < NB) predS[tid] = pred0[b0 + tid];
    if (tid < NB * NCELL) { int b = tid >> 3, c = tid & 7; gateS[b][c] = gate0[(b0 + b) * NCELL + c]; }

    // ---- register-resident W1 slice (f16): 20 m x 4 j x 2 h2 = 160 VGPRs ----
    h2 w1r[MEM][4][2];
    #pragma unroll
    for (int m = 0; m < MEM; ++m)
        #pragma unroll
        for (int jj = 0; jj < 4; ++jj) {
            const float* wp = &W1[(size_t)(j0 + jj) * 2580 + m * 129 + c0];
            h2 w0, w1v;
            w0[0] = (_Float16)wp[0]; w0[1] = (_Float16)wp[1];
            w1v[0] = (_Float16)wp[2]; w1v[1] = (_Float16)wp[3];
            w1r[m][jj][0] = w0; w1r[m][jj][1] = w1v;
        }
    __syncthreads();

    int head = 0;
    #pragma unroll 1
    for (int t = 0; t < S_LEN; ++t) {
        head = (head == 0) ? (MEM - 1) : (head - 1);

        // ---- Phase A (tid<256): 8 expert LSTM cells ----
        if (tid < 256) {
            int b = tid >> 7, c = (tid >> 4) & 7, h = tid & 15;
            float xv = xS[b][t];
            const float4* ep = (const float4*)&ehS[b][0];
            float4 e0 = ep[0], e1v = ep[1], e2 = ep[2], e3 = ep[3];
            float zg[4];
            #pragma unroll
            for (int gi = 0; gi < 4; ++gi) {
                int g = c * 64 + gi * 16 + h;
                const float* wr = &Whh_l[g * 20];
                float z = bias_l[g] + xv * Wih_l[g];
                z += dot4(e0, *(const float4*)&wr[0]) + dot4(e1v, *(const float4*)&wr[4])
                   + dot4(e2, *(const float4*)&wr[8]) + dot4(e3, *(const float4*)&wr[12]);
                zg[gi] = z;
            }
            float cc = ecS[b][h];
            float c2 = sigm(zg[1]) * cc + sigm(zg[0]) * tanh_f(zg[2]);
            float hv = sigm(zg[3]) * tanh_f(c2);
            nhS[b][c][h] = hv; ncS[b][c][h] = c2;
            ringH[b][head][c * 16 + h] = (_Float16)hv;
            if (tid < NB) errS[tid][head] = xS[tid][t] - predS[tid];
        }
        __syncthreads();

        // ---- Phase B (all 512): e1 partials via register-resident f16 W1 ----
        {
            float acc[NB][4] = {};
            #pragma unroll
            for (int m = 0; m < MEM; ++m) {
                int s = head + m; if (s >= MEM) s -= MEM;
                h4 vA = *(const h4*)&ringH[0][s][c0];
                h4 vB = *(const h4*)&ringH[1][s][c0];
                h2 a0A, a1A, a0B, a1B;
                a0A[0] = vA[0]; a0A[1] = vA[1]; a1A[0] = vA[2]; a1A[1] = vA[3];
                a0B[0] = vB[0]; a0B[1] = vB[1]; a1B[0] = vB[2]; a1B[1] = vB[3];
                #pragma unroll
                for (int jj = 0; jj < 4; ++jj) {
                    acc[0][jj] = dot2acc(a0A, w1r[m][jj][0], acc[0][jj]);
                    acc[0][jj] = dot2acc(a1A, w1r[m][jj][1], acc[0][jj]);
                    acc[1][jj] = dot2acc(a0B, w1r[m][jj][0], acc[1][jj]);
                    acc[1][jj] = dot2acc(a1B, w1r[m][jj][1], acc[1][jj]);
                }
            }
            *(float4*)&red[0][kg][j0] = make_float4(acc[0][0], acc[0][1], acc[0][2], acc[0][3]);
            *(float4*)&red[1][kg][j0] = make_float4(acc[1][0], acc[1][1], acc[1][2], acc[1][3]);
        }
        __syncthreads();

        // ---- Phase R (tid<128): reduce split-K + f32 error column + bias + relu ----
        if (tid < 128) {
            int bb = tid >> 6, j = tid & 63;
            float s0 = 0.f, s1 = 0.f, s2 = 0.f, s3 = 0.f;
            #pragma unroll
            for (int g = 0; g < 8; ++g) {
                s0 += red[bb][4 * g + 0][j];
                s1 += red[bb][4 * g + 1][j];
                s2 += red[bb][4 * g + 2][j];
                s3 += red[bb][4 * g + 3][j];
            }
            float v = b1_l[j] + ((s0 + s1) + (s2 + s3));
            float u0 = 0.f, u1 = 0.f;
            #pragma unroll
            for (int m = 0; m < MEM; m += 2) {
                int sa = head + m; if (sa >= MEM) sa -= MEM;
                int sb = head + m + 1; if (sb >= MEM) sb -= MEM;
                u0 = fmaf(Werr_l[m * 64 + j], errS[bb][sa], u0);
                u1 = fmaf(Werr_l[(m + 1) * 64 + j], errS[bb][sb], u1);
            }
            e1S[bb][j] = fmaxf(v + u0 + u1, 0.f);
        }
        __syncthreads();

        // ---- Tail (wave 0 only; intra-wave LDS ordering, no barriers inside) ----
        if (tid < 64) {
            const int j = tid;
            // ai (lanes 0-31) and expert heads o (lanes 32-47)
            if (j < 32) {
                int bb = j >> 4, i = j & 15;
                const float4* epq = (const float4*)&e1S[bb][0];
                float s = b2_l[i];
                #pragma unroll
                for (int q = 0; q < 16; ++q) s += dot4(*(const float4*)&W2_l[i * 68 + q * 4], epq[q]);
                aiS[bb][i] = fmaxf(s, 0.f);
            } else if (j < 48) {
                int q = j - 32, bb = q >> 3, c = q & 7;
                const float4* np = (const float4*)&nhS[bb][c][0];
                const float4* wp = (const float4*)&Wo_l[c][0];
                float s = bo_l[c];
                #pragma unroll
                for (int q4 = 0; q4 < 4; ++q4) s += dot4(np[q4], wp[q4]);
                oS[bb][c] = s;
            }
            // 2-layer agent LSTM: lanes 0-31 = (bb, h), each computes its 4 gates
            #pragma unroll
            for (int l = 0; l < 2; ++l) {
                if (j < 32) {
                    int bb = j >> 4, h = j & 15;
                    const float4* ip = (l == 0) ? (const float4*)&aiS[bb][0]
                                                : (const float4*)&ahS[0][bb][0];
                    const float4* hp = (const float4*)&ahS[l][bb][0];
                    float4 i0 = ip[0], i1 = ip[1], i2 = ip[2], i3 = ip[3];
                    float4 h0 = hp[0], h1 = hp[1], h2v = hp[2], h3 = hp[3];
                    float zg[4];
                    #pragma unroll
                    for (int gi = 0; gi < 4; ++gi) {
                        int g = gi * 16 + h;
                        const float* wi = &WaI[l][g * 20];
                        const float* wh = &WaH[l][g * 20];
                        float z = ba_l[l][g];
                        z += dot4(i0, *(const float4*)&wi[0]) + dot4(i1, *(const float4*)&wi[4])
                           + dot4(i2, *(const float4*)&wi[8]) + dot4(i3, *(const float4*)&wi[12]);
                        z += dot4(h0, *(const float4*)&wh[0]) + dot4(h1, *(const float4*)&wh[4])
                           + dot4(h2v, *(const float4*)&wh[8]) + dot4(h3, *(const float4*)&wh[12]);
                        zg[gi] = z;
                    }
                    float c2 = sigm(zg[1]) * acS[l][bb][h] + sigm(zg[0]) * tanh_f(zg[2]);
                    acS[l][bb][h] = c2;
                    ahS[l][bb][h] = sigm(zg[3]) * tanh_f(c2);
                }
            }
            // gate logits + softmax + theta blend (lanes 0-15)
            if (j < 16) {
                int bb = j >> 3, c = j & 7;
                const float4* hp = (const float4*)&ahS[1][bb][0];
                const float4* wg = (const float4*)&Wg_l[c][0];
                float s = bg_l[c];
                #pragma unroll
                for (int q = 0; q < 4; ++q) s += dot4(wg[q], hp[q]);
                glog[bb][c] = s;
                float4 ga = *(const float4*)&glog[bb][0];
                float4 gb = *(const float4*)&glog[bb][4];
                float mx = fmaxf(fmaxf(fmaxf(ga.x, ga.y), fmaxf(ga.z, ga.w)),
                                 fmaxf(fmaxf(gb.x, gb.y), fmaxf(gb.z, gb.w)));
                float sum = __expf(ga.x - mx) + __expf(ga.y - mx) + __expf(ga.z - mx) + __expf(ga.w - mx)
                          + __expf(gb.x - mx) + __expf(gb.y - mx) + __expf(gb.z - mx) + __expf(gb.w - mx);
                float p = __expf(s - mx) / sum;
                float th = 0.f;
                #pragma unroll
                for (int m = 0; m < 10; ++m) {
                    int sl = head + m; if (sl >= MEM) sl -= MEM;
                    th += fabsf(errS[bb][sl]);
                }
                th *= 0.25f;
                th = fminf(fmaxf(th, 0.f), 1.f);
                gateS[bb][c] = p * th + gateS[bb][c] * (1.f - th);
            }
            // combine (lanes 0-31) + pred/out (lanes 32-33)
            if (j < 32) {
                int bb = j >> 4, h = j & 15;
                float se = 0.f, sc = 0.f;
                #pragma unroll
                for (int c = 0; c < 8; ++c) {
                    float g = gateS[bb][c];
                    se = fmaf(g, nhS[bb][c][h], se);
                    sc = fmaf(g, ncS[bb][c][h], sc);
                }
                ehS[bb][h] = se; ecS[bb][h] = sc;
            } else if (j < 32 + NB) {
                int bb = j - 32;
                float s = 0.f;
                #pragma unroll
                for (int c = 0; c < 8; ++c) s = fmaf(gateS[bb][c], oS[bb][c], s);
                predS[bb] = s;
                out[(b0 + bb) * S_LEN + t] = s;
            }
        }
        __syncthreads();
    }
}

extern "C" void kernel_launch(void* const* d_in, const int* in_sizes, int n_in,
                              void* d_out, int out_size, void* d_ws, size_t ws_size,
                              hipStream_t stream) {
    const float* xp    = (const float*)d_in[0];
    const float* pred0 = (const float*)d_in[1];
    const float* gate0 = (const float*)d_in[2];
    const float* W_ih  = (const float*)d_in[3];
    const float* W_hh  = (const float*)d_in[4];
    const float* b_ih  = (const float*)d_in[5];
    const float* b_hh  = (const float*)d_in[6];
    const float* W_o   = (const float*)d_in[7];
    const float* b_o   = (const float*)d_in[8];
    const float* W1    = (const float*)d_in[9];
    const float* b1    = (const float*)d_in[10];
    const float* W2    = (const float*)d_in[11];
    const float* b2    = (const float*)d_in[12];
    const float* Wg    = (const float*)d_in[13];
    const float* bg    = (const float*)d_in[14];
    const float* Wa_ih = (const float*)d_in[15];
    const float* Wa_hh = (const float*)d_in[16];
    const float* ba_ih = (const float*)d_in[17];
    const float* ba_hh = (const float*)d_in[18];

    mmoe_kernel<<<512 / NB, NTHR, 0, stream>>>(
        xp, pred0, gate0, W_ih, W_hh, b_ih, b_hh, W_o, b_o,
        W1, b1, W2, b2, Wg, bg, Wa_ih, Wa_hh, ba_ih, ba_hh,
        (float*)d_out);
}